// Round 3
// baseline (58.039 us; speedup 1.0000x reference)
//
#include <hip/hip_runtime.h>

#define BB 4
#define CC 64
#define HH 128
#define WW 256

// One wave = one (b, h, dy): 64 lanes x 4 cols = full W row, 9 dx in regs.
// No LDS, no barriers: waves are fully independent; latency hidden by
// unrolled in-flight loads + 18 waves/CU.
__global__ __launch_bounds__(576, 5) void corr_kernel(
    const float* __restrict__ first,
    const float* __restrict__ second,
    float* __restrict__ out)
{
  const int tid  = threadIdx.x;
  const int lane = tid & 63;
  const int wv   = tid >> 6;                 // 0..8 = dy+4
  // XCD-aware mapping: contiguous 16-row h band per XCD for L2 locality.
  const int bid  = blockIdx.x;
  const int idx  = bid >> 3;                 // 0..63
  const int h    = (bid & 7) * 16 + (idx & 15);
  const int b    = idx >> 4;                 // 0..3
  const int l4   = lane * 4;

  const size_t plane = (size_t)HH * WW;
  float* obase = out + (((size_t)b * 81 + (size_t)wv * 9) * HH + (size_t)h) * WW + l4;

  const int gh = h + wv - 4;                 // this wave's second row
  if (gh < 0 || gh >= HH) {                  // whole row OOB -> zeros
    const float4 z = make_float4(0.f, 0.f, 0.f, 0.f);
#pragma unroll
    for (int dx = 0; dx < 9; ++dx)
      *(float4*)(obase + (size_t)dx * plane) = z;
    return;
  }

  const float* frow = first  + ((size_t)b * CC * HH + (size_t)h)  * WW;
  const float* srow = second + ((size_t)b * CC * HH + (size_t)gh) * WW;

  // Window cols l4-4 .. l4+7: three aligned float4 (left/mid/right).
  // Edge lanes clamp the address (stay in-bounds) and zero the value.
  const bool zL = (lane == 0), zR = (lane == 63);
  const int offL = zL ? l4 : l4 - 4;
  const int offR = zR ? l4 : l4 + 4;

  float acc[9][4];
#pragma unroll
  for (int dx = 0; dx < 9; ++dx)
#pragma unroll
    for (int i = 0; i < 4; ++i) acc[dx][i] = 0.0f;

#pragma unroll 2
  for (int c = 0; c < CC; ++c) {
    const size_t cp = (size_t)c * plane;
    float4 f  = *(const float4*)(frow + cp + l4);
    float4 aL = *(const float4*)(srow + cp + offL);
    float4 aM = *(const float4*)(srow + cp + l4);
    float4 aR = *(const float4*)(srow + cp + offR);
    if (zL) { aL.x = 0.f; aL.y = 0.f; aL.z = 0.f; aL.w = 0.f; }
    if (zR) { aR.x = 0.f; aR.y = 0.f; aR.z = 0.f; aR.w = 0.f; }

    const float fv[4]  = {f.x, f.y, f.z, f.w};
    const float sv[12] = {aL.x, aL.y, aL.z, aL.w,
                          aM.x, aM.y, aM.z, aM.w,
                          aR.x, aR.y, aR.z, aR.w};
#pragma unroll
    for (int dx = 0; dx < 9; ++dx)
#pragma unroll
      for (int i = 0; i < 4; ++i)
        acc[dx][i] = fmaf(fv[i], sv[i + dx], acc[dx][i]);
  }

  const float sc = 1.0f / (float)CC;
#pragma unroll
  for (int dx = 0; dx < 9; ++dx) {
    float4 v = make_float4(acc[dx][0] * sc, acc[dx][1] * sc,
                           acc[dx][2] * sc, acc[dx][3] * sc);
    *(float4*)(obase + (size_t)dx * plane) = v;
  }
}

extern "C" void kernel_launch(void* const* d_in, const int* in_sizes, int n_in,
                              void* d_out, int out_size, void* d_ws, size_t ws_size,
                              hipStream_t stream) {
  const float* first  = (const float*)d_in[0];
  const float* second = (const float*)d_in[1];
  float* out = (float*)d_out;
  (void)in_sizes; (void)n_in; (void)out_size; (void)d_ws; (void)ws_size;
  corr_kernel<<<dim3(BB * HH), dim3(576), 0, stream>>>(first, second, out);
}